// Round 3
// baseline (124.797 us; speedup 1.0000x reference)
//
#include <hip/hip_runtime.h>

// Hapke BRDF — elementwise, N=1M.
// R7: block-level LDS staging of the six AoS (N,3) arrays.
// Evidence: R4 (1pt/thread, scalar loads, 26us) vs R6 (2pt/thread, dwordx2,
// ~24.5us) — per-thread ILP is NOT the limiter. Kernel runs at ~4.0 TB/s vs
// 6.3 achievable (fill kernels in the same profile hit 6.5 TB/s). Theory:
// strided per-thread AoS loads (12-24B lane stride, 12-21 VMEM insts) limit
// memory-system efficiency. Fix: stage each block's 6x3KB AoS slices into LDS
// via fully dense dwordx4 (192 lanes x float4 per array, 6 VMEM insts/thread),
// compute from LDS (stride-3 dword reads = 2-way bank aliasing = free).
// theta/h/B0 remain direct coalesced dword loads. VGPR stays ~50 -> high occ;
// LDS 18KB/block -> 4+ blocks/CU interleave stage/compute phases.
// Math is operation-for-operation identical to R4 — no accuracy delta.

#define PIF  3.14159265358979323846f
#define EPSF 1e-5f

typedef float v4f __attribute__((ext_vector_type(4)));

__device__ __forceinline__ float rcp(float x)  { return __builtin_amdgcn_rcpf(x); }
__device__ __forceinline__ float rsq(float x)  { return __builtin_amdgcn_rsqf(x); }
__device__ __forceinline__ float sqf(float x)  { return __builtin_amdgcn_sqrtf(x); }
__device__ __forceinline__ float nz(float y, float r) { return (y != y) ? r : y; }
__device__ __forceinline__ float clamp1(float x) { return fminf(fmaxf(x, -1.0f), 1.0f); }
// Abramowitz-Stegun 4.4.45: |err| <= 6.7e-5 rad. phi only feeds phi/PI * E1
// inside a denominator >= ~0.9 — error impact ~2e-5, far under threshold slack.
__device__ __forceinline__ float acos_poly(float x) {
    float a = fabsf(x);
    float r = sqf(1.0f - a) *
              (1.5707288f + a * (-0.2121144f + a * (0.0742610f + a * (-0.0187293f))));
    return (x >= 0.0f) ? r : (PIF - r);
}

__device__ __forceinline__ void hapke_point(
    float lx, float ly, float lz,
    float vx, float vy, float vz,
    float nx, float ny, float nzc,
    float th, float hh, float B0v,
    float w0, float w1, float w2,
    float b0, float b1, float b2,
    float c0, float c1, float c2,
    float outv[3])
{
    // ci, cv in [0,1] (l,v flipped into normal's hemisphere by setup)
    float ci  = clamp1(nx*lx + ny*ly + nzc*lz);
    float cvv = clamp1(nx*vx + ny*vy + nzc*vz);
    float cg  = clamp1(lx*vx + ly*vy + lz*vz);
    float si  = sqf(1.0f - ci*ci);           // sin(acos x) — exact
    float sv  = sqf(1.0f - cvv*cvv);
    float cphi = clamp1((cg - ci*cvv) * rcp(si*sv + 1e-8f));
    float phipi = acos_poly(cphi) * (1.0f / PIF);

    // ff = exp(-2 tan((phi+EPS)/2)); cphi==-1 -> inf -> NaN -> shad=0 (matches ref)
    float ffu = (1.0f - cphi) * rcp(1.0f + cphi);
    float ff  = (cphi <= -1.0f) ? __builtin_inff() : __expf(-2.0f * sqf(ffu));

    float s = __sinf(th + EPSF), cth = __cosf(th + EPSF);
    float tt     = s * rcp(cth);             // tan(th+EPS); reused for tan(th), diff <= 2e-5
    float cot_th = cth * rcp(s);
    float cot_i  = ci * rcp(si);             // si=0 -> inf -> E*=0 (ref limit)
    float cot_e  = cvv * rcp(sv);

    float E1i = nz(__expf(-(2.0f/PIF) * cot_th * cot_i), 0.0f);
    float E1e = nz(__expf(-(2.0f/PIF) * cot_th * cot_e), 0.0f);
    float ct2 = cot_th * cot_th;
    float E2i = nz(__expf(-(1.0f/PIF) * ct2 * cot_i*cot_i), 0.0f);
    float E2e = nz(__expf(-(1.0f/PIF) * ct2 * cot_e*cot_e), 0.0f);

    float chit = rsq(1.0f + PIF * tt * tt);
    float etai = nz(chit * (ci  + si * tt * (E2i * rcp(2.0f - E1i))), 0.0f);
    float etae = nz(chit * (cvv + sv * tt * (E2e * rcp(2.0f - E1e))), 0.0f);

    float sp2 = 0.5f * (1.0f - cphi);        // sin^2(phi/2) — exact half-angle
    bool  ile = (ci >= cvv);                 // sza <= vza
    float Ea  = ile ? E1e : E1i;             // shared denominator: select, then ONE rcp
    float Eb  = ile ? E1i : E1e;
    float rd  = rcp(2.0f - Ea - phipi * Eb);
    float ymu  = (ile ? (E2e - sp2*E2i)      : (cphi*E2i + sp2*E2e)) * rd;
    float ymu0 = (ile ? (cphi*E2e + sp2*E2i) : (E2i - sp2*E2e)) * rd;
    float cv_e = nz(chit * (cvv + sv * tt * ymu ), cvv);  // _mu_eff
    float ci_e = nz(chit * (ci  + si * tt * ymu0), ci);   // _mu0_eff

    // _S (shadowing)
    float r_etai = rcp(etai), r_etae = rcp(etae);
    float ci_etai = ci * r_etai, cv_etae = cvv * r_etae;
    float temp = cv_e * r_etae * ci_etai * chit;
    float den  = 1.0f - ff + ff * chit * (ile ? ci_etai : cv_etae);
    float shad = nz(temp * rcp(den), 0.0f);  // ff=inf -> den=NaN -> 0 (matches ref)

    // B0/(1 + tan(g/2)/h) + 1 = B0*h/(h + tg2) + 1; tan(g/2)=sqrt((1-cg)/(1+cg))
    float tg2 = sqf((1.0f - cg) * rcp(1.0f + cg));
    float B   = B0v * hh * rcp(hh + tg2) + 1.0f;
    float tmp1 = ci_e * rcp((ci_e + cv_e) * ci);

    float logi = 0.5f * __logf(fabsf((1.0f + ci_e) * rcp(ci_e)));
    float loge = 0.5f * __logf(fabsf((1.0f + cv_e) * rcp(cv_e)));

    const float wk3[3] = {w0, w1, w2};
    const float bk3[3] = {b0, b1, b2};
    const float ck3[3] = {c0, c1, c2};
    #pragma unroll
    for (int k = 0; k < 3; ++k) {
        float wk = wk3[k], bk = bk3[k], ck = ck3[k];
        float b2 = bk * bk, bx = bk * cg;
        float t1 = 1.0f - 2.0f*bx + b2;      // >= (1-0.8)^2 = 0.04 > 0
        float t2 = 1.0f + 2.0f*bx + b2;
        float q1 = t1 * sqf(t1) + 1e-6f;
        float q2 = t2 * sqf(t2) + 1e-6f;
        float P  = (1.0f - b2) * (ck*q2 + (1.0f - ck)*q1) * rcp(q1*q2);
        float gamma = sqf(1.0f - wk);
        float ro = (1.0f - gamma) * rcp(1.0f + gamma);
        float Hi = nz(rcp(1.0f - wk*ci_e*(ro + (1.0f - 2.0f*ro*ci_e)*logi)), 1.0f);
        float Hv = nz(rcp(1.0f - wk*cv_e*(ro + (1.0f - 2.0f*ro*cv_e)*loge)), 1.0f);
        float tmp2 = P * B + Hi * Hv - 1.0f;
        outv[k] = wk * 0.25f * tmp1 * tmp2 * shad;   // w / HPK_SCL
    }
}

#define PTS 256   // points per block == threads per block

__global__ __launch_bounds__(256, 4)
void hapke_kernel(const float* __restrict__ pts2l, const float* __restrict__ pts2c,
                  const float* __restrict__ normal, const float* __restrict__ w,
                  const float* __restrict__ b, const float* __restrict__ c,
                  const float* __restrict__ theta, const float* __restrict__ h,
                  const float* __restrict__ B0, float* __restrict__ out, int N)
{
    // 6 arrays x 256 pts x 3 floats = 18432 B LDS
    __shared__ __align__(16) float sL[PTS*3];
    __shared__ __align__(16) float sV[PTS*3];
    __shared__ __align__(16) float sN[PTS*3];
    __shared__ __align__(16) float sW[PTS*3];
    __shared__ __align__(16) float sB[PTS*3];
    __shared__ __align__(16) float sC[PTS*3];

    const int tid = threadIdx.x;
    const int blockStart = blockIdx.x * PTS;
    const int p = blockStart + tid;

    if (blockStart + PTS <= N) {
        // Full block: dense dwordx4 staging. 768 floats = 192 float4 per array;
        // waves 0-2 load, wave 3 idles (wave-uniform branch, no divergence).
        const int f4base = blockIdx.x * (PTS * 3 / 4);   // float4 index
        if (tid < PTS * 3 / 4) {
            ((v4f*)sL)[tid] = ((const v4f*)pts2l )[f4base + tid];
            ((v4f*)sV)[tid] = ((const v4f*)pts2c )[f4base + tid];
            ((v4f*)sN)[tid] = ((const v4f*)normal)[f4base + tid];
            ((v4f*)sW)[tid] = ((const v4f*)w     )[f4base + tid];
            ((v4f*)sB)[tid] = ((const v4f*)b     )[f4base + tid];
            ((v4f*)sC)[tid] = ((const v4f*)c     )[f4base + tid];
        }
        // Independent coalesced dword loads; issue before the barrier.
        float th = theta[p], hh = h[p], zz = B0[p];
        __syncthreads();

        const int t3 = tid * 3;   // stride-3 dword LDS reads: 2-way bank alias = free
        float o[3];
        hapke_point(sL[t3], sL[t3+1], sL[t3+2],
                    sV[t3], sV[t3+1], sV[t3+2],
                    sN[t3], sN[t3+1], sN[t3+2],
                    th, hh, zz,
                    sW[t3], sW[t3+1], sW[t3+2],
                    sB[t3], sB[t3+1], sB[t3+2],
                    sC[t3], sC[t3+1], sC[t3+2], o);

        const int i3 = p * 3;
        __builtin_nontemporal_store(o[0], &out[i3]);
        __builtin_nontemporal_store(o[1], &out[i3+1]);
        __builtin_nontemporal_store(o[2], &out[i3+2]);
    } else if (p < N) {
        // Tail block (not taken at N=1048576): direct scalar path.
        const int i3 = p * 3;
        float o[3];
        hapke_point(pts2l[i3], pts2l[i3+1], pts2l[i3+2],
                    pts2c[i3], pts2c[i3+1], pts2c[i3+2],
                    normal[i3], normal[i3+1], normal[i3+2],
                    theta[p], h[p], B0[p],
                    w[i3], w[i3+1], w[i3+2],
                    b[i3], b[i3+1], b[i3+2],
                    c[i3], c[i3+1], c[i3+2], o);
        out[i3] = o[0]; out[i3+1] = o[1]; out[i3+2] = o[2];
    }
}

extern "C" void kernel_launch(void* const* d_in, const int* in_sizes, int n_in,
                              void* d_out, int out_size, void* d_ws, size_t ws_size,
                              hipStream_t stream) {
    const float* pts2l  = (const float*)d_in[0];
    const float* pts2c  = (const float*)d_in[1];
    const float* normal = (const float*)d_in[2];
    const float* w      = (const float*)d_in[3];
    const float* b      = (const float*)d_in[4];
    const float* c      = (const float*)d_in[5];
    const float* theta  = (const float*)d_in[6];
    const float* h      = (const float*)d_in[7];
    const float* B0     = (const float*)d_in[8];
    float* out = (float*)d_out;

    int N = in_sizes[6];
    const int block = 256;
    int grid = (N + block - 1) / block;   // one point per thread, PTS per block
    hapke_kernel<<<grid, block, 0, stream>>>(pts2l, pts2c, normal, w, b, c,
                                             theta, h, B0, out, N);
}